// Round 6
// baseline (1052.476 us; speedup 1.0000x reference)
//
#include <hip/hip_runtime.h>

#define N_NODES   50000
#define N_EDGES   1600000
#define N_GRAPHS  512
#define LAYERS    3
#define D         128
#define EF        16
#define BN_EPS    1e-5f

typedef _Float16 half2v __attribute__((ext_vector_type(2)));
typedef short bf16x8 __attribute__((ext_vector_type(8)));
typedef float f32x4 __attribute__((ext_vector_type(4)));

__device__ __forceinline__ float fdot2h(unsigned a, half2v b, float c) {
#if __has_builtin(__builtin_amdgcn_fdot2)
    return __builtin_amdgcn_fdot2(__builtin_bit_cast(half2v, a), b, c, false);
#else
    half2v av = __builtin_bit_cast(half2v, a);
    return fmaf((float)av[0], (float)b[0], fmaf((float)av[1], (float)b[1], c));
#endif
}

__device__ __forceinline__ unsigned pack_h2(float x, float y) {
    half2v t; t[0] = (_Float16)x; t[1] = (_Float16)y;
    return __builtin_bit_cast(unsigned, t);
}

__device__ __forceinline__ unsigned short f2bf(float f) {   // RNE f32->bf16
    unsigned u = __builtin_bit_cast(unsigned, f);
    u += 0x7FFF + ((u >> 16) & 1);
    return (unsigned short)(u >> 16);
}

__device__ __forceinline__ float bf2f(unsigned short u) {
    return __builtin_bit_cast(float, (unsigned)u << 16);
}

// ---------------------------------------------------------------------------
// CSR build step 1: histogram of dst (counts pre-zeroed).
// ---------------------------------------------------------------------------
__global__ __launch_bounds__(256) void hist_kernel(
    const int* __restrict__ dst, int* __restrict__ counts)
{
    int e = blockIdx.x * 256 + threadIdx.x;
    atomicAdd(&counts[dst[e]], 1);
}

// ---------------------------------------------------------------------------
// CSR build step 2: exclusive scan -> offsets[N_NODES+1] + cursor copy.
// ---------------------------------------------------------------------------
__global__ __launch_bounds__(1024) void scan_kernel(
    const int* __restrict__ counts, int* __restrict__ offsets,
    int* __restrict__ cursor)
{
    __shared__ int part[1024];
    const int t = threadIdx.x;
    const int CH = (N_NODES + 1023) / 1024;   // 49
    const int lo = t * CH;
    const int hi = (lo + CH < N_NODES) ? lo + CH : N_NODES;
    int s = 0;
    for (int i = lo; i < hi; ++i) s += counts[i];
    part[t] = s;
    __syncthreads();
    for (int off = 1; off < 1024; off <<= 1) {
        int v = (t >= off) ? part[t - off] : 0;
        __syncthreads();
        part[t] += v;
        __syncthreads();
    }
    int run = (t > 0) ? part[t - 1] : 0;
    for (int i = lo; i < hi; ++i) {
        offsets[i] = run;
        cursor[i]  = run;
        run += counts[i];
    }
    if (t == 1023) offsets[N_NODES] = run;
}

// ---------------------------------------------------------------------------
// CSR build step 3: scatter edges into dst-sorted order; edge_attr -> f16.
// ---------------------------------------------------------------------------
__global__ __launch_bounds__(256) void scatter_kernel(
    const int* __restrict__ src, const int* __restrict__ dst,
    const float* __restrict__ edge_attr,
    int* __restrict__ cursor, int* __restrict__ sorted_src,
    uint4* __restrict__ sorted_eah)
{
    int e = blockIdx.x * 256 + threadIdx.x;
    int d = dst[e];
    int pos = atomicAdd(&cursor[d], 1);
    sorted_src[pos] = src[e];
    const float4* ea = (const float4*)(edge_attr + (size_t)e * EF);
    float4 a0 = ea[0], a1 = ea[1], a2 = ea[2], a3 = ea[3];
    uint4 o0, o1;
    o0.x = pack_h2(a0.x, a0.y); o0.y = pack_h2(a0.z, a0.w);
    o0.z = pack_h2(a1.x, a1.y); o0.w = pack_h2(a1.z, a1.w);
    o1.x = pack_h2(a2.x, a2.y); o1.y = pack_h2(a2.z, a2.w);
    o1.z = pack_h2(a3.x, a3.y); o1.w = pack_h2(a3.z, a3.w);
    sorted_eah[(size_t)pos * 2]     = o0;
    sorted_eah[(size_t)pos * 2 + 1] = o1;
}

// ---------------------------------------------------------------------------
// Graph offsets: batch is sorted; goff[g] = lower_bound(batch, g), goff[512]=N.
// ---------------------------------------------------------------------------
__global__ __launch_bounds__(512) void goff_kernel(
    const int* __restrict__ batch, int* __restrict__ goff)
{
    const int g = threadIdx.x;
    int lo = 0, hi = N_NODES;
    while (lo < hi) {
        int mid = (lo + hi) >> 1;
        if (batch[mid] < g) lo = mid + 1; else hi = mid;
    }
    goff[g] = lo;
    if (g == 0) goff[N_GRAPHS] = N_NODES;
}

// ---------------------------------------------------------------------------
// Weight prep: transpose W1/W2 (all layers) to bf16 Wt[out][k], once per call.
// ---------------------------------------------------------------------------
__global__ __launch_bounds__(256) void wprep_kernel(
    const float* __restrict__ W1, const float* __restrict__ W2,
    unsigned short* __restrict__ Wt)
{
    const int matid = blockIdx.x;          // l*2 + (0:W1, 1:W2)
    const int l = matid >> 1;
    const float* srcm = (matid & 1) ? (W2 + (size_t)l * D * D)
                                    : (W1 + (size_t)l * D * D);
    unsigned short* out = Wt + (size_t)matid * D * D;
    for (int i = 0; i < 64; ++i) {
        int idx = threadIdx.x + i * 256;
        int k = idx >> 7, n = idx & 127;
        out[n * D + k] = f2bf(srcm[idx]);
    }
}

// ---------------------------------------------------------------------------
// x -> bf16 (once per call).
// ---------------------------------------------------------------------------
__global__ __launch_bounds__(256) void xprep_kernel(
    const float* __restrict__ x, unsigned short* __restrict__ xb)
{
    int i = blockIdx.x * 256 + threadIdx.x;   // grid exact: 6.4M/256
    xb[i] = f2bf(x[i]);
}

// ---------------------------------------------------------------------------
// Per-layer aggregation (gather, no atomics, no LDS):
//   zin_b[n][j] = bf16( h[n][j] + sum_e relu(h[src_e][j] + dot16(ea_e, elW[:,j]) + elb[j]) )
// Edge data (ea, src) addresses are block-uniform -> compiler emits s_load;
// v_dot2 takes the SGPR operand directly. h gathered as bf16 (256 B/row).
// ---------------------------------------------------------------------------
__global__ __launch_bounds__(128) void aggr_kernel(
    const unsigned short* __restrict__ h_b,    // [N][128] bf16
    const uint4* __restrict__ sorted_ea,       // 2 x uint4 per edge (f16x16)
    const int*   __restrict__ sorted_src,
    const int*   __restrict__ offsets,
    const float* __restrict__ elW,   // [16][128] this layer
    const float* __restrict__ elb,
    unsigned short* __restrict__ zin_b)
{
    const int j = threadIdx.x;       // feature 0..127
    const int n = blockIdx.x;

    half2v w2[8];
    #pragma unroll
    for (int k = 0; k < 8; ++k) {
        half2v t;
        t[0] = (_Float16)elW[(2*k    ) * D + j];
        t[1] = (_Float16)elW[(2*k + 1) * D + j];
        w2[k] = t;
    }
    const float bias = elb[j];

    const int beg = offsets[n];
    const int end = offsets[n + 1];

    float acc = 0.0f;
    #pragma unroll 2
    for (int e = beg; e < end; ++e) {
        const uint4 p0 = sorted_ea[(size_t)e * 2];      // uniform -> s_load
        const uint4 p1 = sorted_ea[(size_t)e * 2 + 1];  // uniform -> s_load
        const int   s  = sorted_src[e];                 // uniform -> s_load
        const unsigned short hv = h_b[(size_t)s * D + j];
        float dot = bias;
        dot = fdot2h(p0.x, w2[0], dot);
        dot = fdot2h(p0.y, w2[1], dot);
        dot = fdot2h(p0.z, w2[2], dot);
        dot = fdot2h(p0.w, w2[3], dot);
        dot = fdot2h(p1.x, w2[4], dot);
        dot = fdot2h(p1.y, w2[5], dot);
        dot = fdot2h(p1.z, w2[6], dot);
        dot = fdot2h(p1.w, w2[7], dot);
        acc += fmaxf(bf2f(hv) + dot, 0.0f);
    }
    zin_b[(size_t)n * D + j] = f2bf(bf2f(h_b[(size_t)n * D + j]) + acc);
}

// ---------------------------------------------------------------------------
// Fused node MLP via MFMA (bf16 in, fp32 accumulate):
//   hout_b = bf16(relu(relu(BN(zin@W1+b1))@W2 + b2))
// 128 threads = 2 waves, 64 nodes/block; B-frags from global (L2-resident).
// Layouts (verified m89/m120): A[m=lane&15][k=quad*8+j]; C/D row=quad*4+reg,
// col=lane&15. LDS = zmid only (17.4 KB).
// ---------------------------------------------------------------------------
__global__ __launch_bounds__(128) void node_mlp(
    const unsigned short* __restrict__ zin_b,   // [N][128] bf16
    const unsigned short* __restrict__ W1t,     // [128 out][128 k] bf16
    const float* __restrict__ b1,
    const float* __restrict__ bng, const float* __restrict__ bnb,
    const float* __restrict__ bnm, const float* __restrict__ bnv,
    const unsigned short* __restrict__ W2t,
    const float* __restrict__ b2,
    unsigned short* __restrict__ hout_b)
{
    __shared__ unsigned short zmid[64 * 136];   // 17.4 KB
    __shared__ float scale_s[128], shift_s[128], b2_s[128];

    const int tid  = threadIdx.x;
    const int wv   = tid >> 6;        // 0..1
    const int lane = tid & 63;
    const int q    = lane >> 4;
    const int m    = lane & 15;
    const int node0 = blockIdx.x * 64;

    {
        float sc = bng[tid] * rsqrtf(bnv[tid] + BN_EPS);
        scale_s[tid] = sc;
        shift_s[tid] = b1[tid] * sc + bnb[tid] - bnm[tid] * sc;  // fold b1 into BN
        b2_s[tid]    = b2[tid];
    }

    // A fragments straight from global bf16 zin
    bf16x8 a[2][4];
    #pragma unroll
    for (int sub = 0; sub < 2; ++sub) {
        int node = node0 + wv * 32 + sub * 16 + m;
        if (node >= N_NODES) node = N_NODES - 1;
        const uint4* zrow = (const uint4*)(zin_b + (size_t)node * D);
        #pragma unroll
        for (int k = 0; k < 4; ++k)
            a[sub][k] = __builtin_bit_cast(bf16x8, zrow[k * 4 + q]);
    }

    f32x4 acc[2][8];
    #pragma unroll
    for (int s2 = 0; s2 < 2; ++s2)
        #pragma unroll
        for (int t = 0; t < 8; ++t)
            acc[s2][t] = (f32x4){0.f, 0.f, 0.f, 0.f};

    __syncthreads();   // scale_s/shift_s ready

    // GEMM 1: B-frags from global W1t
    #pragma unroll
    for (int t = 0; t < 8; ++t) {
        const unsigned short* wrow = W1t + (size_t)(t * 16 + m) * D;
        bf16x8 bfr[4];
        #pragma unroll
        for (int k = 0; k < 4; ++k)
            bfr[k] = __builtin_bit_cast(bf16x8, *(const uint4*)&wrow[k * 32 + q * 8]);
        #pragma unroll
        for (int sub = 0; sub < 2; ++sub) {
            acc[sub][t] = __builtin_amdgcn_mfma_f32_16x16x32_bf16(a[sub][0], bfr[0], acc[sub][t], 0, 0, 0);
            acc[sub][t] = __builtin_amdgcn_mfma_f32_16x16x32_bf16(a[sub][1], bfr[1], acc[sub][t], 0, 0, 0);
            acc[sub][t] = __builtin_amdgcn_mfma_f32_16x16x32_bf16(a[sub][2], bfr[2], acc[sub][t], 0, 0, 0);
            acc[sub][t] = __builtin_amdgcn_mfma_f32_16x16x32_bf16(a[sub][3], bfr[3], acc[sub][t], 0, 0, 0);
        }
    }

    // epilogue 1: BN + relu -> zmid (bf16, C/D layout -> LDS)
    #pragma unroll
    for (int sub = 0; sub < 2; ++sub)
        #pragma unroll
        for (int t = 0; t < 8; ++t) {
            int col = t * 16 + m;
            float sc = scale_s[col], sh = shift_s[col];
            #pragma unroll
            for (int rr = 0; rr < 4; ++rr) {
                float v = fmaxf(acc[sub][t][rr] * sc + sh, 0.f);
                int row = wv * 32 + sub * 16 + q * 4 + rr;
                zmid[row * 136 + col] = f2bf(v);
            }
        }

    __syncthreads();   // zmid complete

    // A2 frags from zmid
    bf16x8 a2[2][4];
    #pragma unroll
    for (int sub = 0; sub < 2; ++sub) {
        const unsigned short* zr = &zmid[(wv * 32 + sub * 16 + m) * 136];
        #pragma unroll
        for (int k = 0; k < 4; ++k)
            a2[sub][k] = __builtin_bit_cast(bf16x8, *(const uint4*)&zr[k * 32 + q * 8]);
    }

    #pragma unroll
    for (int s2 = 0; s2 < 2; ++s2)
        #pragma unroll
        for (int t = 0; t < 8; ++t)
            acc[s2][t] = (f32x4){0.f, 0.f, 0.f, 0.f};

    // GEMM 2: B-frags from global W2t
    #pragma unroll
    for (int t = 0; t < 8; ++t) {
        const unsigned short* wrow = W2t + (size_t)(t * 16 + m) * D;
        bf16x8 bfr[4];
        #pragma unroll
        for (int k = 0; k < 4; ++k)
            bfr[k] = __builtin_bit_cast(bf16x8, *(const uint4*)&wrow[k * 32 + q * 8]);
        #pragma unroll
        for (int sub = 0; sub < 2; ++sub) {
            acc[sub][t] = __builtin_amdgcn_mfma_f32_16x16x32_bf16(a2[sub][0], bfr[0], acc[sub][t], 0, 0, 0);
            acc[sub][t] = __builtin_amdgcn_mfma_f32_16x16x32_bf16(a2[sub][1], bfr[1], acc[sub][t], 0, 0, 0);
            acc[sub][t] = __builtin_amdgcn_mfma_f32_16x16x32_bf16(a2[sub][2], bfr[2], acc[sub][t], 0, 0, 0);
            acc[sub][t] = __builtin_amdgcn_mfma_f32_16x16x32_bf16(a2[sub][3], bfr[3], acc[sub][t], 0, 0, 0);
        }
    }

    // epilogue 2: bias + relu -> hout (bf16). No atomics.
    #pragma unroll
    for (int sub = 0; sub < 2; ++sub)
        #pragma unroll
        for (int rr = 0; rr < 4; ++rr) {
            int node = node0 + wv * 32 + sub * 16 + q * 4 + rr;
            if (node < N_NODES) {
                unsigned short* hrow = hout_b + (size_t)node * D;
                #pragma unroll
                for (int t = 0; t < 8; ++t) {
                    int col = t * 16 + m;
                    hrow[col] = f2bf(fmaxf(acc[sub][t][rr] + b2_s[col], 0.f));
                }
            }
        }
}

// ---------------------------------------------------------------------------
// Pool: segmented sum over sorted batch (bf16 in, fp32 out). No atomics.
// ---------------------------------------------------------------------------
__global__ __launch_bounds__(128) void pool_kernel(
    const unsigned short* __restrict__ hout_b, const int* __restrict__ goff,
    float* __restrict__ pool, int layer_off)
{
    const int g = blockIdx.x;
    const int j = threadIdx.x;
    const int beg = goff[g], end = goff[g + 1];
    float acc = 0.0f;
    for (int r = beg; r < end; ++r)
        acc += bf2f(hout_b[(size_t)r * D + j]);
    pool[g * (LAYERS * D) + layer_off + j] = acc;
}

// ---------------------------------------------------------------------------
// Head: out[g] = relu(pool[g] @ lin1_W + lin1_b) @ lin2_W + lin2_b
// ---------------------------------------------------------------------------
__global__ __launch_bounds__(384) void head_kernel(
    const float* __restrict__ pool,
    const float* __restrict__ lin1W,
    const float* __restrict__ lin1b,
    const float* __restrict__ lin2W,
    const float* __restrict__ lin2b,
    float*       __restrict__ out)
{
    __shared__ float gs[LAYERS * D];
    __shared__ float red[LAYERS * D];
    const int g   = blockIdx.x;
    const int tid = threadIdx.x;
    gs[tid] = pool[g * (LAYERS * D) + tid];
    __syncthreads();

    float acc = lin1b[tid];
    #pragma unroll 4
    for (int k = 0; k < LAYERS * D; ++k)
        acc = fmaf(gs[k], lin1W[k * (LAYERS * D) + tid], acc);
    acc = fmaxf(acc, 0.0f);
    float p = acc * lin2W[tid];

    red[tid] = p;
    __syncthreads();
    if (tid < 128) red[tid] = red[tid] + red[tid + 128] + red[tid + 256];
    __syncthreads();
    if (tid < 64) {
        float v = red[tid] + red[tid + 64];
        v += __shfl_down(v, 32);
        v += __shfl_down(v, 16);
        v += __shfl_down(v, 8);
        v += __shfl_down(v, 4);
        v += __shfl_down(v, 2);
        v += __shfl_down(v, 1);
        if (tid == 0) out[g] = v + lin2b[0];
    }
}

// ---------------------------------------------------------------------------
extern "C" void kernel_launch(void* const* d_in, const int* in_sizes, int n_in,
                              void* d_out, int out_size, void* d_ws, size_t ws_size,
                              hipStream_t stream)
{
    const float* x         = (const float*)d_in[0];
    const float* edge_attr = (const float*)d_in[1];
    const float* elW       = (const float*)d_in[2];
    const float* elb       = (const float*)d_in[3];
    const float* W1        = (const float*)d_in[4];
    const float* b1        = (const float*)d_in[5];
    const float* bn_g      = (const float*)d_in[6];
    const float* bn_b      = (const float*)d_in[7];
    const float* bn_mean   = (const float*)d_in[8];
    const float* bn_var    = (const float*)d_in[9];
    const float* W2        = (const float*)d_in[10];
    const float* b2        = (const float*)d_in[11];
    const float* lin1W     = (const float*)d_in[12];
    const float* lin1b     = (const float*)d_in[13];
    const float* lin2W     = (const float*)d_in[14];
    const float* lin2b     = (const float*)d_in[15];
    const int*   ei        = (const int*)d_in[16];
    const int*   batch     = (const int*)d_in[17];
    const int*   src = ei;
    const int*   dst = ei + N_EDGES;

    // Workspace layout, all 16B-aligned:
    float*          pool       = (float*)d_ws;                              // G*384 f32
    unsigned short* xb         = (unsigned short*)(pool + (size_t)N_GRAPHS * LAYERS * D);
    unsigned short* hA_b       = xb   + (size_t)N_NODES * D;                // bf16
    unsigned short* zin_b      = hA_b + (size_t)N_NODES * D;                // bf16
    unsigned short* Wt         = zin_b + (size_t)N_NODES * D;               // 6*16384 bf16
    unsigned*       sorted_eah = (unsigned*)(Wt + 6 * D * D);               // E*8 u32
    int*            sorted_src = (int*)(sorted_eah + (size_t)N_EDGES * 8);
    int*            counts     = sorted_src + N_EDGES;
    int*            offsets    = counts + N_NODES;
    int*            cursor     = offsets + N_NODES + 4;
    int*            goff       = cursor + N_NODES + 4;                      // 513 ints

    hipMemsetAsync(counts, 0, (size_t)N_NODES * sizeof(int), stream);

    // --- once-per-call prep ---
    wprep_kernel<<<6, 256, 0, stream>>>(W1, W2, Wt);
    xprep_kernel<<<(N_NODES * D) / 256, 256, 0, stream>>>(x, xb);
    goff_kernel<<<1, 512, 0, stream>>>(batch, goff);
    hist_kernel<<<N_EDGES / 256, 256, 0, stream>>>(dst, counts);
    scan_kernel<<<1, 1024, 0, stream>>>(counts, offsets, cursor);
    scatter_kernel<<<N_EDGES / 256, 256, 0, stream>>>(
        src, dst, edge_attr, cursor, sorted_src, (uint4*)sorted_eah);

    const unsigned short* hin_b = xb;
    for (int l = 0; l < LAYERS; ++l) {
        aggr_kernel<<<N_NODES, 128, 0, stream>>>(
            hin_b, (const uint4*)sorted_eah, sorted_src, offsets,
            elW + (size_t)l * EF * D, elb + l * D, zin_b);
        node_mlp<<<(N_NODES + 63) / 64, 128, 0, stream>>>(
            zin_b,
            Wt + (size_t)(l * 2)     * D * D, b1 + l * D,
            bn_g + l * D, bn_b + l * D, bn_mean + l * D, bn_var + l * D,
            Wt + (size_t)(l * 2 + 1) * D * D, b2 + l * D,
            hA_b);
        pool_kernel<<<N_GRAPHS, 128, 0, stream>>>(hA_b, goff, pool, l * D);
        hin_b = hA_b;
    }

    head_kernel<<<N_GRAPHS, LAYERS * D, 0, stream>>>(
        pool, lin1W, lin1b, lin2W, lin2b, (float*)d_out);
}